// Round 5
// baseline (1052.390 us; speedup 1.0000x reference)
//
#include <hip/hip_runtime.h>

// Problem constants (B, Cin, Cout, H, W) = (8, 256, 256, 128, 128)
#define BATCH 8
#define CIN   256
#define COUT  256
#define HH    128
#define WW    128
#define HW    (HH*WW)          // 16384

typedef __bf16 bf16x8 __attribute__((ext_vector_type(8)));
typedef float  f32x4  __attribute__((ext_vector_type(4)));
typedef unsigned short u16x8 __attribute__((ext_vector_type(8)));

__device__ __forceinline__ unsigned short f2bf(float f) {
    unsigned u = __float_as_uint(f);
    unsigned r = (u + 0x7fffu + ((u >> 16) & 1u)) >> 16;   // round-to-nearest-even
    return (unsigned short)r;
}

// Swizzle for 8x16B-slot rows at 128B row stride. Must permute fully for BOTH
// access patterns: conv lB writes (w stride 4 across lanes) and MFMA reads
// (row stride 1 across lanes). (r^(r>>2))&7 is a bijection on r mod 8 AND on
// (4t) mod 32 -> {0,5,2,7,4,1,6,3}: full spread in both cases. Plain r&7
// collapses to 2 values on stride-4 lanes (16-way conflict).
__device__ __forceinline__ int swz8(int r) { return (r ^ (r >> 2)) & 7; }

// ---------------------------------------------------------------------------
// FUSED kernel: per block (b, h, mt) computes out[b][mt*128 .. +127][h][0..127].
// K-loop over 4 chunks of 64 cin:
//   A-prep: lA[row][k] = bf16(pw + delta)   (swizzled, ds_write_b128)
//   conv:   lB[w][c]   = bf16(dwconv3x3(x)) (swizzled, ds_write_b128; each
//           thread owns 4 w x 8 contiguous c so the c-dim packs into u16x8)
//   barrier; 2x16 MFMA 16x16x32; barrier.
// Eliminates the Tt (67MB) global roundtrip, the Wb prep kernel, and 2 of 3
// launches. Floor: x 134MB read + out 134MB write ~= 45us.
// XCD swizzle: XCD owns batch; mt fastest (x-tile shared), h next (halo L2).
// ---------------------------------------------------------------------------
__global__ __launch_bounds__(256, 4) void fused_kernel(
    const float* __restrict__ x, const float* __restrict__ dw,
    const float* __restrict__ delta, const float* __restrict__ pw,
    float* __restrict__ out)
{
    __shared__ unsigned short lA[128 * 64];   // [m-row][slot^swz8(row)] 16KB
    __shared__ unsigned short lB[128 * 64];   // [w-row][slot^swz8(w)]   16KB

    const int b     = (int)blockIdx.x & 7;    // batch == XCD
    const int inner = (int)blockIdx.x >> 3;   // 0..255 within XCD
    const int mt    = inner & 1;              // Cout half, fastest
    const int h     = inner >> 1;             // 0..127
    const int tid   = threadIdx.x;

    // MFMA decomposition (identical to the proven R1 gemm)
    const int lane = tid & 63;
    const int wv   = tid >> 6;
    const int wm   = (wv & 1) * 64;
    const int wn   = (wv >> 1) * 64;
    const int q    = lane >> 4;     // quad 0..3
    const int rrow = lane & 15;

    // conv decomposition
    const int wq = tid & 31;        // w-quad: w0..w0+3
    const int cs = tid >> 5;        // 0..7: 8 contiguous channels cs*8..cs*8+7
    const int w0 = wq * 4;

    f32x4 acc[4][4] = {};

    const float* deltab = delta + (size_t)b * COUT * CIN;

    for (int kc = 0; kc < 4; ++kc) {
        // ---- A-prep: lA[row][k] = bf16(pw[mt*128+row][kc*64+k] + delta[b][...]) ----
        #pragma unroll
        for (int r = 0; r < 4; ++r) {
            const int i   = r * 256 + tid;    // 16B chunk id 0..1023
            const int row = i >> 3;           // 0..127
            const int ls  = i & 7;            // logical slot
            const size_t goff = (size_t)(mt * 128 + row) * CIN + kc * 64 + ls * 8;
            const float4 p0 = *(const float4*)(pw + goff);
            const float4 p1 = *(const float4*)(pw + goff + 4);
            const float4 d0 = *(const float4*)(deltab + goff);
            const float4 d1 = *(const float4*)(deltab + goff + 4);
            u16x8 v;
            v[0] = f2bf(p0.x + d0.x); v[1] = f2bf(p0.y + d0.y);
            v[2] = f2bf(p0.z + d0.z); v[3] = f2bf(p0.w + d0.w);
            v[4] = f2bf(p1.x + d1.x); v[5] = f2bf(p1.y + d1.y);
            v[6] = f2bf(p1.z + d1.z); v[7] = f2bf(p1.w + d1.w);
            *(u16x8*)&lA[row * 64 + (ls ^ swz8(row)) * 8] = v;
        }

        // ---- conv: this chunk's 64 channels; thread: 4 w x 8 contiguous c ----
        u16x8 v0, v1, v2, v3;   // bf16 outputs for w0..w0+3, elems = ci
        #pragma unroll
        for (int ci = 0; ci < 8; ++ci) {
            const int gc = kc * 64 + cs * 8 + ci;        // global cin
            const float* xp = x + ((size_t)(b * CIN + gc)) * HW;
            const float* kp = dw + (size_t)gc * 9;
            float a0 = 0.f, a1 = 0.f, a2 = 0.f, a3 = 0.f;
            #pragma unroll
            for (int dy = 0; dy < 3; ++dy) {
                const int r = h + dy - 1;
                float4 v = {0.f, 0.f, 0.f, 0.f};
                if (r >= 0 && r < HH) v = *(const float4*)(xp + r * WW + w0);
                float lft = __shfl_up(v.w, 1);    // lane-1's last element
                float rgt = __shfl_down(v.x, 1);  // lane+1's first element
                if (wq == 0)  lft = 0.f;          // w=-1 pad
                if (wq == 31) rgt = 0.f;          // w=128 pad
                const float k0 = kp[dy * 3 + 0], k1 = kp[dy * 3 + 1], k2 = kp[dy * 3 + 2];
                a0 += k0 * lft + k1 * v.x + k2 * v.y;
                a1 += k0 * v.x + k1 * v.y + k2 * v.z;
                a2 += k0 * v.y + k1 * v.z + k2 * v.w;
                a3 += k0 * v.z + k1 * v.w + k2 * rgt;
            }
            v0[ci] = f2bf(a0); v1[ci] = f2bf(a1);
            v2[ci] = f2bf(a2); v3[ci] = f2bf(a3);
        }
        // c-group cs is logical slot cs; 4 rows w0..w0+3
        *(u16x8*)&lB[(w0 + 0) * 64 + (cs ^ swz8(w0 + 0)) * 8] = v0;
        *(u16x8*)&lB[(w0 + 1) * 64 + (cs ^ swz8(w0 + 1)) * 8] = v1;
        *(u16x8*)&lB[(w0 + 2) * 64 + (cs ^ swz8(w0 + 2)) * 8] = v2;
        *(u16x8*)&lB[(w0 + 3) * 64 + (cs ^ swz8(w0 + 3)) * 8] = v3;

        __syncthreads();

        // ---- MFMA: K=64 in 2 kk-steps ----
        #pragma unroll
        for (int kk = 0; kk < 2; ++kk) {
            bf16x8 af[4], bfv[4];
            #pragma unroll
            for (int i = 0; i < 4; ++i) {
                const int ra = wm + i * 16 + rrow;
                const int rb = wn + i * 16 + rrow;
                af[i]  = *(const bf16x8*)&lA[ra * 64 + ((kk * 4 + q) ^ swz8(ra)) * 8];
                bfv[i] = *(const bf16x8*)&lB[rb * 64 + ((kk * 4 + q) ^ swz8(rb)) * 8];
            }
            #pragma unroll
            for (int i = 0; i < 4; ++i)
                #pragma unroll
                for (int j = 0; j < 4; ++j)
                    acc[i][j] = __builtin_amdgcn_mfma_f32_16x16x32_bf16(af[i], bfv[j], acc[i][j], 0, 0, 0);
        }
        __syncthreads();   // lA/lB reused next chunk
    }

    // epilogue: C/D map col=lane&15, row=quad*4+reg (proven in R1 gemm)
    float* outp = out + ((size_t)(b * COUT + mt * 128 + wm)) * HW + (size_t)h * WW + wn;
    #pragma unroll
    for (int i = 0; i < 4; ++i)
        #pragma unroll
        for (int j = 0; j < 4; ++j)
            #pragma unroll
            for (int rr = 0; rr < 4; ++rr)
                outp[(size_t)(i * 16 + q * 4 + rr) * HW + j * 16 + rrow] = acc[i][j][rr];
}

// ---------------------------------------------------------------------------
extern "C" void kernel_launch(void* const* d_in, const int* in_sizes, int n_in,
                              void* d_out, int out_size, void* d_ws, size_t ws_size,
                              hipStream_t stream)
{
    const float* x     = (const float*)d_in[0];   // (8,256,128,128)
    const float* delta = (const float*)d_in[1];   // (8,256,256,1,1)
    const float* dw    = (const float*)d_in[2];   // (256,1,3,3)
    const float* pw    = (const float*)d_in[3];   // (256,256,1,1)
    float* out = (float*)d_out;                   // (8,256,128,128)

    // fully fused: no workspace needed
    fused_kernel<<<dim3(2048), dim3(256), 0, stream>>>(x, dw, delta, pw, out);
}

// Round 6
// 523.320 us; speedup vs baseline: 2.0110x; 2.0110x over previous
//
#include <hip/hip_runtime.h>

// Problem constants (B, Cin, Cout, H, W) = (8, 256, 256, 128, 128)
#define BATCH 8
#define CIN   256
#define COUT  256
#define HH    128
#define WW    128
#define HW    (HH*WW)          // 16384

typedef __bf16 bf16x8 __attribute__((ext_vector_type(8)));
typedef float  f32x4  __attribute__((ext_vector_type(4)));
typedef unsigned short u16x8 __attribute__((ext_vector_type(8)));

__device__ __forceinline__ unsigned short f2bf(float f) {
    unsigned u = __float_as_uint(f);
    unsigned r = (u + 0x7fffu + ((u >> 16) & 1u)) >> 16;   // round-to-nearest-even
    return (unsigned short)r;
}

// Swizzle for 8x16B-slot rows at 128B row stride. Must permute fully for BOTH
// access patterns: conv lB writes (w stride 4 across lanes) and MFMA reads
// (row stride 1 across lanes). (r^(r>>2))&7 is a bijection on r mod 8 AND on
// (4t) mod 32 -> {0,5,2,7,4,1,6,3}: full spread in both cases. Plain r&7
// collapses to 2 values on stride-4 lanes (16-way conflict).
__device__ __forceinline__ int swz8(int r) { return (r ^ (r >> 2)) & 7; }

// ---------------------------------------------------------------------------
// FUSED kernel: per block (b, h, mt) computes out[b][mt*128 .. +127][h][0..127].
// R5 post-mortem: __launch_bounds__(256,4) capped VGPRs at 64 -> ~100 VGPRs of
// live state spilled to scratch -> hbm_bytes 2.74 GB (10x floor), 905 us.
// R6: drop the wave-minimum (VGPR_Count was the ONLY change). Expected ~160
// VGPR, 3 blocks/CU (VGPR-bound; LDS allows 5).
// K-loop over 4 chunks of 64 cin:
//   A-prep: lA[row][k] = bf16(pw + delta)   (swizzled, ds_write_b128)
//   conv:   lB[w][c]   = bf16(dwconv3x3(x)) (swizzled, ds_write_b128)
//   barrier; 2x16 MFMA 16x16x32; barrier.
// Floor: x 134MB read + out 134MB write ~= 45us.
// XCD swizzle: XCD owns batch; mt fastest (x-tile shared), h next (halo L2).
// ---------------------------------------------------------------------------
__global__ __launch_bounds__(256) void fused_kernel(
    const float* __restrict__ x, const float* __restrict__ dw,
    const float* __restrict__ delta, const float* __restrict__ pw,
    float* __restrict__ out)
{
    __shared__ unsigned short lA[128 * 64];   // [m-row][slot^swz8(row)] 16KB
    __shared__ unsigned short lB[128 * 64];   // [w-row][slot^swz8(w)]   16KB

    const int b     = (int)blockIdx.x & 7;    // batch == XCD
    const int inner = (int)blockIdx.x >> 3;   // 0..255 within XCD
    const int mt    = inner & 1;              // Cout half, fastest
    const int h     = inner >> 1;             // 0..127
    const int tid   = threadIdx.x;

    // MFMA decomposition (identical to the proven R1 gemm)
    const int lane = tid & 63;
    const int wv   = tid >> 6;
    const int wm   = (wv & 1) * 64;
    const int wn   = (wv >> 1) * 64;
    const int q    = lane >> 4;     // quad 0..3
    const int rrow = lane & 15;

    // conv decomposition
    const int wq = tid & 31;        // w-quad: w0..w0+3
    const int cs = tid >> 5;        // 0..7: 8 contiguous channels cs*8..cs*8+7
    const int w0 = wq * 4;

    f32x4 acc[4][4] = {};

    const float* deltab = delta + (size_t)b * COUT * CIN;

    for (int kc = 0; kc < 4; ++kc) {
        // ---- A-prep: lA[row][k] = bf16(pw[mt*128+row][kc*64+k] + delta[b][...]) ----
        #pragma unroll
        for (int r = 0; r < 4; ++r) {
            const int i   = r * 256 + tid;    // 16B chunk id 0..1023
            const int row = i >> 3;           // 0..127
            const int ls  = i & 7;            // logical slot
            const size_t goff = (size_t)(mt * 128 + row) * CIN + kc * 64 + ls * 8;
            const float4 p0 = *(const float4*)(pw + goff);
            const float4 p1 = *(const float4*)(pw + goff + 4);
            const float4 d0 = *(const float4*)(deltab + goff);
            const float4 d1 = *(const float4*)(deltab + goff + 4);
            u16x8 v;
            v[0] = f2bf(p0.x + d0.x); v[1] = f2bf(p0.y + d0.y);
            v[2] = f2bf(p0.z + d0.z); v[3] = f2bf(p0.w + d0.w);
            v[4] = f2bf(p1.x + d1.x); v[5] = f2bf(p1.y + d1.y);
            v[6] = f2bf(p1.z + d1.z); v[7] = f2bf(p1.w + d1.w);
            *(u16x8*)&lA[row * 64 + (ls ^ swz8(row)) * 8] = v;
        }

        // ---- conv: this chunk's 64 channels; thread: 4 w x 8 contiguous c ----
        u16x8 v0, v1, v2, v3;   // bf16 outputs for w0..w0+3, elems = ci
        #pragma unroll
        for (int ci = 0; ci < 8; ++ci) {
            const int gc = kc * 64 + cs * 8 + ci;        // global cin
            const float* xp = x + ((size_t)(b * CIN + gc)) * HW;
            const float* kp = dw + (size_t)gc * 9;
            float a0 = 0.f, a1 = 0.f, a2 = 0.f, a3 = 0.f;
            #pragma unroll
            for (int dy = 0; dy < 3; ++dy) {
                const int r = h + dy - 1;
                float4 v = {0.f, 0.f, 0.f, 0.f};
                if (r >= 0 && r < HH) v = *(const float4*)(xp + r * WW + w0);
                float lft = __shfl_up(v.w, 1);    // lane-1's last element
                float rgt = __shfl_down(v.x, 1);  // lane+1's first element
                if (wq == 0)  lft = 0.f;          // w=-1 pad
                if (wq == 31) rgt = 0.f;          // w=128 pad
                const float k0 = kp[dy * 3 + 0], k1 = kp[dy * 3 + 1], k2 = kp[dy * 3 + 2];
                a0 += k0 * lft + k1 * v.x + k2 * v.y;
                a1 += k0 * v.x + k1 * v.y + k2 * v.z;
                a2 += k0 * v.y + k1 * v.z + k2 * v.w;
                a3 += k0 * v.z + k1 * v.w + k2 * rgt;
            }
            v0[ci] = f2bf(a0); v1[ci] = f2bf(a1);
            v2[ci] = f2bf(a2); v3[ci] = f2bf(a3);
        }
        // c-group cs is logical slot cs; 4 rows w0..w0+3
        *(u16x8*)&lB[(w0 + 0) * 64 + (cs ^ swz8(w0 + 0)) * 8] = v0;
        *(u16x8*)&lB[(w0 + 1) * 64 + (cs ^ swz8(w0 + 1)) * 8] = v1;
        *(u16x8*)&lB[(w0 + 2) * 64 + (cs ^ swz8(w0 + 2)) * 8] = v2;
        *(u16x8*)&lB[(w0 + 3) * 64 + (cs ^ swz8(w0 + 3)) * 8] = v3;

        __syncthreads();

        // ---- MFMA: K=64 in 2 kk-steps ----
        #pragma unroll
        for (int kk = 0; kk < 2; ++kk) {
            bf16x8 af[4], bfv[4];
            #pragma unroll
            for (int i = 0; i < 4; ++i) {
                const int ra = wm + i * 16 + rrow;
                const int rb = wn + i * 16 + rrow;
                af[i]  = *(const bf16x8*)&lA[ra * 64 + ((kk * 4 + q) ^ swz8(ra)) * 8];
                bfv[i] = *(const bf16x8*)&lB[rb * 64 + ((kk * 4 + q) ^ swz8(rb)) * 8];
            }
            #pragma unroll
            for (int i = 0; i < 4; ++i)
                #pragma unroll
                for (int j = 0; j < 4; ++j)
                    acc[i][j] = __builtin_amdgcn_mfma_f32_16x16x32_bf16(af[i], bfv[j], acc[i][j], 0, 0, 0);
        }
        __syncthreads();   // lA/lB reused next chunk
    }

    // epilogue: C/D map col=lane&15, row=quad*4+reg (proven in R1 gemm)
    float* outp = out + ((size_t)(b * COUT + mt * 128 + wm)) * HW + (size_t)h * WW + wn;
    #pragma unroll
    for (int i = 0; i < 4; ++i)
        #pragma unroll
        for (int j = 0; j < 4; ++j)
            #pragma unroll
            for (int rr = 0; rr < 4; ++rr)
                outp[(size_t)(i * 16 + q * 4 + rr) * HW + j * 16 + rrow] = acc[i][j][rr];
}

// ---------------------------------------------------------------------------
extern "C" void kernel_launch(void* const* d_in, const int* in_sizes, int n_in,
                              void* d_out, int out_size, void* d_ws, size_t ws_size,
                              hipStream_t stream)
{
    const float* x     = (const float*)d_in[0];   // (8,256,128,128)
    const float* delta = (const float*)d_in[1];   // (8,256,256,1,1)
    const float* dw    = (const float*)d_in[2];   // (256,1,3,3)
    const float* pw    = (const float*)d_in[3];   // (256,256,1,1)
    float* out = (float*)d_out;                   // (8,256,128,128)

    // fully fused: no workspace needed
    fused_kernel<<<dim3(2048), dim3(256), 0, stream>>>(x, dw, delta, pw, out);
}